// Round 1
// baseline (447.108 us; speedup 1.0000x reference)
//
#include <hip/hip_runtime.h>
#include <hip/hip_bf16.h>
#include <stdint.h>

typedef __attribute__((ext_vector_type(4))) float f32x4;
typedef __attribute__((ext_vector_type(8))) short bf16x8;

#define DIM   768
#define NH    12
#define HD    64
#define NB    8
#define SEQ   512
#define SCALE 0.125f

#define MFMA16 __builtin_amdgcn_mfma_f32_16x16x32_bf16

__device__ __forceinline__ unsigned short f2bf(float f) {
    union { float f; uint32_t u; } v; v.f = f;
    uint32_t u = v.u;
    return (unsigned short)((u + 0x7FFFu + ((u >> 16) & 1u)) >> 16);
}

// ---------------- prep: f32 -> bf16 convert ----------------
__global__ void k_convert(const float* __restrict__ in, unsigned short* __restrict__ out, int n4) {
    int i = blockIdx.x * blockDim.x + threadIdx.x;
    if (i >= n4) return;
    float4 f = reinterpret_cast<const float4*>(in)[i];
    ushort4 o;
    o.x = f2bf(f.x); o.y = f2bf(f.y); o.z = f2bf(f.z); o.w = f2bf(f.w);
    reinterpret_cast<ushort4*>(out)[i] = o;
}

// ---------------- prep: W[768][768] f32 -> WT[768][768] bf16 (transposed) ----------------
__global__ void k_wt(const float* __restrict__ W, unsigned short* __restrict__ WT) {
    __shared__ float t[32][33];
    int n0 = blockIdx.x * 32, k0 = blockIdx.y * 32;
    int tx = threadIdx.x, ty = threadIdx.y; // 32 x 8
#pragma unroll
    for (int j = 0; j < 4; ++j)
        t[ty + 8 * j][tx] = W[(k0 + ty + 8 * j) * DIM + n0 + tx];
    __syncthreads();
#pragma unroll
    for (int j = 0; j < 4; ++j)
        WT[(n0 + ty + 8 * j) * DIM + k0 + tx] = f2bf(t[tx][ty + 8 * j]);
}

// ---------------- prep: pack MLP params [u][20] = {W1[0..5][u], b1[u], W2[u][0..11], pad} ----------------
__global__ void k_pack(const float* __restrict__ W1, const float* __restrict__ b1,
                       const float* __restrict__ W2, float* __restrict__ P) {
    int u = blockIdx.x * blockDim.x + threadIdx.x;
    if (u >= DIM) return;
#pragma unroll
    for (int f = 0; f < 6; ++f) P[u * 20 + f] = W1[f * DIM + u];
    P[u * 20 + 6] = b1[u];
#pragma unroll
    for (int h = 0; h < 12; ++h) P[u * 20 + 7 + h] = W2[u * 12 + h];
    P[u * 20 + 19] = 0.f;
}

// ---------------- pairwise bias MLP: bias_ws[h][q][k] ----------------
__global__ void __launch_bounds__(256) k_mlp(const float* __restrict__ qc, const float* __restrict__ kc,
                                             const float* __restrict__ P, const float* __restrict__ b2,
                                             float* __restrict__ bias_out) {
    int p = blockIdx.x * 256 + threadIdx.x;      // 262144 pairs
    int qi = p >> 9, ki = p & 511;
    float dx = qc[2 * qi] - kc[2 * ki];
    float dy = qc[2 * qi + 1] - kc[2 * ki + 1];
    float r2 = fabsf(dx), r3 = fabsf(dy), r4 = dx * dx, r5 = dy * dy;
    float acc[12];
#pragma unroll
    for (int h = 0; h < 12; ++h) acc[h] = 0.f;
#pragma unroll 2
    for (int u = 0; u < DIM; ++u) {
        const float4* pu = reinterpret_cast<const float4*>(P + u * 20);
        float4 a = pu[0], b = pu[1], c = pu[2], d = pu[3], e = pu[4];
        float pre = b.z + dx * a.x + dy * a.y + r2 * a.z + r3 * a.w + r4 * b.x + r5 * b.y;
        // tanh-approx GELU via sigmoid: gelu(x) = x * sigmoid(2*0.7978845608*(x+0.044715x^3))
        float tt = pre * (0.7978845608f + 0.0356774081f * pre * pre);
        float g = pre / (1.0f + __expf(-2.0f * tt));
        acc[0] += g * b.w;  acc[1] += g * c.x;  acc[2] += g * c.y;  acc[3] += g * c.z;
        acc[4] += g * c.w;  acc[5] += g * d.x;  acc[6] += g * d.y;  acc[7] += g * d.z;
        acc[8] += g * d.w;  acc[9] += g * e.x;  acc[10] += g * e.y; acc[11] += g * e.z;
    }
#pragma unroll
    for (int h = 0; h < 12; ++h)
        bias_out[h * (SEQ * SEQ) + p] = acc[h] + b2[h];
}

// ---------------- GEMM: C[m][n] = sum_k X[m][k]*WT[n][k] + bias[n] ----------------
// MODE 0: store bf16 to [B][NH][SEQ][HD] (m->(b,l), n->(h,d));  MODE 1: store f32 row-major [m][n]
template <int MODE>
__global__ void __launch_bounds__(256) k_gemm(const unsigned short* __restrict__ X,
                                              const unsigned short* __restrict__ WT,
                                              const float* __restrict__ bias, void* __restrict__ out) {
    int m0 = blockIdx.x * 64, n0 = blockIdx.y * 64;
    int t = threadIdx.x, lane = t & 63, w = t >> 6;
    int rt2 = w >> 1, ct2 = w & 1;
    int lrow = lane & 15, hi = lane >> 4;
    f32x4 acc[2][2] = {};
    const unsigned short* Xp = X + (m0 + rt2 * 32 + lrow) * DIM + hi * 8;
    const unsigned short* Wp = WT + (n0 + ct2 * 32 + lrow) * DIM + hi * 8;
#pragma unroll 4
    for (int k0 = 0; k0 < DIM; k0 += 32) {
        bf16x8 a0 = *(const bf16x8*)(Xp + k0);
        bf16x8 a1 = *(const bf16x8*)(Xp + 16 * DIM + k0);
        bf16x8 b0 = *(const bf16x8*)(Wp + k0);
        bf16x8 b1 = *(const bf16x8*)(Wp + 16 * DIM + k0);
        acc[0][0] = MFMA16(a0, b0, acc[0][0], 0, 0, 0);
        acc[0][1] = MFMA16(a0, b1, acc[0][1], 0, 0, 0);
        acc[1][0] = MFMA16(a1, b0, acc[1][0], 0, 0, 0);
        acc[1][1] = MFMA16(a1, b1, acc[1][1], 0, 0, 0);
    }
#pragma unroll
    for (int rr = 0; rr < 2; ++rr)
#pragma unroll
        for (int cc = 0; cc < 2; ++cc) {
            int n = n0 + ct2 * 32 + cc * 16 + lrow;
            float bn = bias[n];
#pragma unroll
            for (int r = 0; r < 4; ++r) {
                int m = m0 + rt2 * 32 + rr * 16 + hi * 4 + r;
                float v = acc[rr][cc][r] + bn;
                if (MODE == 0) {
                    int bb = m >> 9, l = m & 511, h = n >> 6, d = n & 63;
                    ((unsigned short*)out)[(((bb * NH + h) * SEQ) + l) * HD + d] = f2bf(v);
                } else {
                    ((float*)out)[m * DIM + n] = v;
                }
            }
        }
}

// ---------------- transpose V: [B,H,SEQ,HD] -> [B,H,HD,SEQ] ----------------
__global__ void k_vt(const unsigned short* __restrict__ v_ws, unsigned short* __restrict__ v_t) {
    int bh = blockIdx.x;
    int lk0 = blockIdx.y * 64;
    int t = threadIdx.x;
    const unsigned short* src = v_ws + bh * SEQ * HD;
    unsigned short* dst = v_t + bh * HD * SEQ;
#pragma unroll
    for (int i = 0; i < 2; ++i) {
        int e = i * 256 + t;            // 0..511
        int dh = e >> 3, c8 = e & 7;
        unsigned short tmp[8];
#pragma unroll
        for (int j = 0; j < 8; ++j)
            tmp[j] = src[(lk0 + c8 * 8 + j) * HD + dh];
        *(uint4*)(dst + dh * SEQ + lk0 + c8 * 8) = *(uint4*)tmp;
    }
}

// ---------------- attention: per (qtile32, h, b) ----------------
__global__ void __launch_bounds__(256) k_attn(const unsigned short* __restrict__ q_ws,
                                              const unsigned short* __restrict__ k_ws,
                                              const unsigned short* __restrict__ v_t,
                                              const float* __restrict__ bias_ws,
                                              unsigned short* __restrict__ attn_out) {
    __shared__ float sm[32 * 516 + 32];   // logits [32][516] + inv[32]
    int qt = blockIdx.x, h = blockIdx.y, b = blockIdx.z;
    int q0 = qt * 32;
    int t = threadIdx.x, lane = t & 63, w = t >> 6;
    int lrow = lane & 15, hi = lane >> 4;
    int bh = b * NH + h;
    const unsigned short* Q = q_ws + (bh * SEQ + q0) * HD;
    const unsigned short* K = k_ws + bh * SEQ * HD;
    const float* Bias = bias_ws + (h * SEQ + q0) * SEQ;

    // phase A: S = Q K^T * SCALE + bias  -> LDS (wave w owns cols [w*128, w*128+128))
    bf16x8 aq[2][2];
#pragma unroll
    for (int rt = 0; rt < 2; ++rt)
#pragma unroll
        for (int ds = 0; ds < 2; ++ds)
            aq[rt][ds] = *(const bf16x8*)(Q + (rt * 16 + lrow) * HD + ds * 32 + hi * 8);

#pragma unroll
    for (int ct = 0; ct < 8; ++ct) {
        f32x4 acc0 = {}, acc1 = {};
        int kk = w * 128 + ct * 16 + lrow;
#pragma unroll
        for (int ds = 0; ds < 2; ++ds) {
            bf16x8 bk = *(const bf16x8*)(K + kk * HD + ds * 32 + hi * 8);
            acc0 = MFMA16(aq[0][ds], bk, acc0, 0, 0, 0);
            acc1 = MFMA16(aq[1][ds], bk, acc1, 0, 0, 0);
        }
        int col = w * 128 + ct * 16 + lrow;
#pragma unroll
        for (int r = 0; r < 4; ++r) {
            int row0 = hi * 4 + r;
            sm[row0 * 516 + col] = acc0[r] * SCALE + Bias[row0 * SEQ + col];
            int row1 = 16 + hi * 4 + r;
            sm[row1 * 516 + col] = acc1[r] * SCALE + Bias[row1 * SEQ + col];
        }
    }
    __syncthreads();

    // phase B: row softmax (8 lanes per row, stride-8 column scan)
    {
        int row = t >> 3, seg = t & 7;
        float mx = -1e30f;
#pragma unroll 8
        for (int i = 0; i < 64; ++i)
            mx = fmaxf(mx, sm[row * 516 + seg + 8 * i]);
        mx = fmaxf(mx, __shfl_xor(mx, 1));
        mx = fmaxf(mx, __shfl_xor(mx, 2));
        mx = fmaxf(mx, __shfl_xor(mx, 4));
        float s = 0.f;
#pragma unroll 8
        for (int i = 0; i < 64; ++i) {
            int idx = row * 516 + seg + 8 * i;
            float pe = __expf(sm[idx] - mx);
            sm[idx] = pe;
            s += pe;
        }
        s += __shfl_xor(s, 1);
        s += __shfl_xor(s, 2);
        s += __shfl_xor(s, 4);
        if (seg == 0) sm[32 * 516 + row] = 1.0f / s;
    }
    __syncthreads();

    // phase C: O = P V  (wave w owns dh cols [w*16, w*16+16))
    const unsigned short* Vt = v_t + bh * HD * SEQ + (w * 16 + lrow) * SEQ;
    f32x4 oacc0 = {}, oacc1 = {};
    for (int kt = 0; kt < 16; ++kt) {
        bf16x8 bv = *(const bf16x8*)(Vt + kt * 32 + hi * 8);
#pragma unroll
        for (int rt = 0; rt < 2; ++rt) {
            const float* ps = &sm[(rt * 16 + lrow) * 516 + kt * 32 + hi * 8];
            float4 p0 = *(const float4*)(ps);
            float4 p1 = *(const float4*)(ps + 4);
            bf16x8 pa;
            pa[0] = (short)f2bf(p0.x); pa[1] = (short)f2bf(p0.y);
            pa[2] = (short)f2bf(p0.z); pa[3] = (short)f2bf(p0.w);
            pa[4] = (short)f2bf(p1.x); pa[5] = (short)f2bf(p1.y);
            pa[6] = (short)f2bf(p1.z); pa[7] = (short)f2bf(p1.w);
            if (rt == 0) oacc0 = MFMA16(pa, bv, oacc0, 0, 0, 0);
            else         oacc1 = MFMA16(pa, bv, oacc1, 0, 0, 0);
        }
    }
#pragma unroll
    for (int r = 0; r < 4; ++r) {
        int row0 = hi * 4 + r;
        float v0 = oacc0[r] * sm[32 * 516 + row0];
        attn_out[(b * SEQ + q0 + row0) * DIM + h * HD + w * 16 + lrow] = f2bf(v0);
        int row1 = 16 + hi * 4 + r;
        float v1 = oacc1[r] * sm[32 * 516 + row1];
        attn_out[(b * SEQ + q0 + row1) * DIM + h * HD + w * 16 + lrow] = f2bf(v1);
    }
}

extern "C" void kernel_launch(void* const* d_in, const int* in_sizes, int n_in,
                              void* d_out, int out_size, void* d_ws, size_t ws_size,
                              hipStream_t stream) {
    const float* query     = (const float*)d_in[0];
    const float* key_value = (const float*)d_in[1];
    const float* qc        = (const float*)d_in[2];
    const float* kc        = (const float*)d_in[3];
    const float* Wq        = (const float*)d_in[4];
    const float* bq        = (const float*)d_in[5];
    const float* Wk        = (const float*)d_in[6];
    const float* bk        = (const float*)d_in[7];
    const float* Wv        = (const float*)d_in[8];
    const float* bv        = (const float*)d_in[9];
    const float* Wo        = (const float*)d_in[10];
    const float* bo        = (const float*)d_in[11];
    const float* W1        = (const float*)d_in[12];
    const float* b1        = (const float*)d_in[13];
    const float* W2        = (const float*)d_in[14];
    const float* b2        = (const float*)d_in[15];

    char* ws = (char*)d_ws;
    unsigned short* Xq   = (unsigned short*)(ws + 0);          // 6291456 B (reused as attn_out)
    unsigned short* Xkv  = (unsigned short*)(ws + 6291456);    // 6291456 B (reused as v_t)
    unsigned short* WqT  = (unsigned short*)(ws + 12582912);
    unsigned short* WkT  = (unsigned short*)(ws + 13762560);
    unsigned short* WvT  = (unsigned short*)(ws + 14942208);
    unsigned short* WoT  = (unsigned short*)(ws + 16121856);
    unsigned short* q_ws = (unsigned short*)(ws + 17301504);
    unsigned short* k_ws = (unsigned short*)(ws + 23592960);
    unsigned short* v_ws = (unsigned short*)(ws + 29884416);
    float* bias_ws       = (float*)(ws + 36175872);            // 12582912 B
    float* params        = (float*)(ws + 48758784);            // 61440 B
    unsigned short* attn_out = Xq;   // Xq dead after Q projection
    unsigned short* v_t      = Xkv;  // Xkv dead after K/V projections

    k_convert<<<dim3(3072), dim3(256), 0, stream>>>(query, Xq, 786432);
    k_convert<<<dim3(3072), dim3(256), 0, stream>>>(key_value, Xkv, 786432);
    k_wt<<<dim3(24, 24), dim3(32, 8), 0, stream>>>(Wq, WqT);
    k_wt<<<dim3(24, 24), dim3(32, 8), 0, stream>>>(Wk, WkT);
    k_wt<<<dim3(24, 24), dim3(32, 8), 0, stream>>>(Wv, WvT);
    k_wt<<<dim3(24, 24), dim3(32, 8), 0, stream>>>(Wo, WoT);
    k_pack<<<dim3(3), dim3(256), 0, stream>>>(W1, b1, W2, params);
    k_mlp<<<dim3(1024), dim3(256), 0, stream>>>(qc, kc, params, b2, bias_ws);
    k_gemm<0><<<dim3(64, 12), dim3(256), 0, stream>>>(Xq, WqT, bq, q_ws);
    k_gemm<0><<<dim3(64, 12), dim3(256), 0, stream>>>(Xkv, WkT, bk, k_ws);
    k_gemm<0><<<dim3(64, 12), dim3(256), 0, stream>>>(Xkv, WvT, bv, v_ws);
    k_vt<<<dim3(96, 8), dim3(256), 0, stream>>>(v_ws, v_t);
    k_attn<<<dim3(16, NH, NB), dim3(256), 0, stream>>>(q_ws, k_ws, v_t, bias_ws, attn_out);
    k_gemm<1><<<dim3(64, 12), dim3(256), 0, stream>>>(attn_out, WoT, bo, d_out);
}

// Round 2
// 340.858 us; speedup vs baseline: 1.3117x; 1.3117x over previous
//
#include <hip/hip_runtime.h>
#include <hip/hip_bf16.h>
#include <stdint.h>

typedef __attribute__((ext_vector_type(4))) float f32x4;
typedef __attribute__((ext_vector_type(8))) short bf16x8;

#define DIM   768
#define NH    12
#define HD    64
#define NB    8
#define SEQ   512
#define SCALE 0.125f

#define MFMA16 __builtin_amdgcn_mfma_f32_16x16x32_bf16

__device__ __forceinline__ unsigned short f2bf(float f) {
    union { float f; uint32_t u; } v; v.f = f;
    uint32_t u = v.u;
    return (unsigned short)((u + 0x7FFFu + ((u >> 16) & 1u)) >> 16);
}

__device__ __forceinline__ unsigned short f2bf_trunc(float f) {
    union { float f; uint32_t u; } v; v.f = f;
    return (unsigned short)(v.u >> 16);
}

// ---------------- prep: f32 -> bf16 convert ----------------
__global__ void k_convert(const float* __restrict__ in, unsigned short* __restrict__ out, int n4) {
    int i = blockIdx.x * blockDim.x + threadIdx.x;
    if (i >= n4) return;
    float4 f = reinterpret_cast<const float4*>(in)[i];
    ushort4 o;
    o.x = f2bf(f.x); o.y = f2bf(f.y); o.z = f2bf(f.z); o.w = f2bf(f.w);
    reinterpret_cast<ushort4*>(out)[i] = o;
}

// ---------------- prep: W[768][768] f32 -> WT[768][768] bf16 (transposed) ----------------
__global__ void k_wt(const float* __restrict__ W, unsigned short* __restrict__ WT) {
    __shared__ float t[32][33];
    int n0 = blockIdx.x * 32, k0 = blockIdx.y * 32;
    int tx = threadIdx.x, ty = threadIdx.y; // 32 x 8
#pragma unroll
    for (int j = 0; j < 4; ++j)
        t[ty + 8 * j][tx] = W[(k0 + ty + 8 * j) * DIM + n0 + tx];
    __syncthreads();
#pragma unroll
    for (int j = 0; j < 4; ++j)
        WT[(n0 + ty + 8 * j) * DIM + k0 + tx] = f2bf(t[tx][ty + 8 * j]);
}

// ---------------- prep: pack MLP params ----------------
// P8: [c][e][g][8] f32, u = c*32+g*8+e, row = {W1[0..5][u], b1[u], pad}
// W2f: [c][lane][e] bf16 frags, lane g=lane>>4, h=lane&15: W2[(c*32+g*8+e)][h], 0 if h>=12
__global__ void k_pack2(const float* __restrict__ W1, const float* __restrict__ b1,
                        const float* __restrict__ W2, float* __restrict__ P8,
                        unsigned short* __restrict__ W2f) {
    int i = blockIdx.x * 256 + threadIdx.x;   // 0..12287
    {
        int c = i >> 9, r = i & 511;
        int lane = r >> 3, e = r & 7;
        int g = lane >> 4, h = lane & 15;
        int u = c * 32 + g * 8 + e;
        W2f[i] = (h < 12) ? f2bf(W2[u * 12 + h]) : (unsigned short)0;
    }
    if (i < DIM) {
        int u = i;
        int c = u >> 5, g = (u >> 3) & 3, e = u & 7;
        int base = ((c * 8 + e) * 4 + g) * 8;
#pragma unroll
        for (int f = 0; f < 6; ++f) P8[base + f] = W1[f * DIM + u];
        P8[base + 6] = b1[u];
        P8[base + 7] = 0.f;
    }
}

// ---------------- pairwise bias MLP via MFMA: bias_ws[h][q][k] ----------------
__global__ void __launch_bounds__(256) k_mlp2(const float* __restrict__ qc, const float* __restrict__ kc,
                                              const float* __restrict__ P8,
                                              const unsigned short* __restrict__ W2f,
                                              const float* __restrict__ b2,
                                              float* __restrict__ bias_out) {
    __shared__ float sp[6144];   // 24 KB params, [c][e][g][8]
    int t = threadIdx.x;
    {
        const float4* src = (const float4*)P8;
        float4* dst = (float4*)sp;
#pragma unroll
        for (int i = 0; i < 6; ++i) dst[i * 256 + t] = src[i * 256 + t];
    }
    int lane = t & 63, w = t >> 6;
    int g = lane >> 4, m = lane & 15;
    int p0 = blockIdx.x * 64 + w * 16;       // wave's 16 consecutive pairs
    int p_feat = p0 + m;
    int qi = p_feat >> 9, ki = p_feat & 511;
    float dx = qc[2 * qi] - kc[2 * ki];
    float dy = qc[2 * qi + 1] - kc[2 * ki + 1];
    float adx = fabsf(dx), ady = fabsf(dy), dx2 = dx * dx, dy2 = dy * dy;
    __syncthreads();

    f32x4 acc = {};
#pragma unroll 2
    for (int c = 0; c < 24; ++c) {
        bf16x8 wb = *(const bf16x8*)(W2f + c * 512 + lane * 8);
        bf16x8 pa;
#pragma unroll
        for (int e = 0; e < 8; ++e) {
            const float4* pr = (const float4*)&sp[((c * 8 + e) * 4 + g) * 8];
            float4 A = pr[0], B4 = pr[1];
            float pre = B4.z + dx * A.x + dy * A.y + adx * A.z + ady * A.w + dx2 * B4.x + dy2 * B4.y;
            float tt = pre * (0.7978845608f + 0.0356774081f * pre * pre);
            float ev = exp2f(tt * -2.885390082f);          // = exp(-2*tt)
            float gv = pre * __builtin_amdgcn_rcpf(1.0f + ev);
            pa[e] = (short)f2bf_trunc(gv);
        }
        acc = MFMA16(pa, wb, acc, 0, 0, 0);
    }
    int h = m;
    if (h < 12) {
        float bb = b2[h];
        float* o = bias_out + h * (SEQ * SEQ) + p0 + g * 4;
#pragma unroll
        for (int r = 0; r < 4; ++r) o[r] = acc[r] + bb;
    }
}

// ---------------- GEMM: C[m][n] = sum_k X[m][k]*WT[n][k] + bias[n] ----------------
// MODE 0: store bf16 to [B][NH][SEQ][HD] (m->(b,l), n->(h,d));  MODE 1: store f32 row-major [m][n]
template <int MODE>
__global__ void __launch_bounds__(256) k_gemm(const unsigned short* __restrict__ X,
                                              const unsigned short* __restrict__ WT,
                                              const float* __restrict__ bias, void* __restrict__ out) {
    int m0 = blockIdx.x * 64, n0 = blockIdx.y * 64;
    int t = threadIdx.x, lane = t & 63, w = t >> 6;
    int rt2 = w >> 1, ct2 = w & 1;
    int lrow = lane & 15, hi = lane >> 4;
    f32x4 acc[2][2] = {};
    const unsigned short* Xp = X + (m0 + rt2 * 32 + lrow) * DIM + hi * 8;
    const unsigned short* Wp = WT + (n0 + ct2 * 32 + lrow) * DIM + hi * 8;
#pragma unroll 4
    for (int k0 = 0; k0 < DIM; k0 += 32) {
        bf16x8 a0 = *(const bf16x8*)(Xp + k0);
        bf16x8 a1 = *(const bf16x8*)(Xp + 16 * DIM + k0);
        bf16x8 b0 = *(const bf16x8*)(Wp + k0);
        bf16x8 b1 = *(const bf16x8*)(Wp + 16 * DIM + k0);
        acc[0][0] = MFMA16(a0, b0, acc[0][0], 0, 0, 0);
        acc[0][1] = MFMA16(a0, b1, acc[0][1], 0, 0, 0);
        acc[1][0] = MFMA16(a1, b0, acc[1][0], 0, 0, 0);
        acc[1][1] = MFMA16(a1, b1, acc[1][1], 0, 0, 0);
    }
#pragma unroll
    for (int rr = 0; rr < 2; ++rr)
#pragma unroll
        for (int cc = 0; cc < 2; ++cc) {
            int n = n0 + ct2 * 32 + cc * 16 + lrow;
            float bn = bias[n];
#pragma unroll
            for (int r = 0; r < 4; ++r) {
                int m = m0 + rt2 * 32 + rr * 16 + hi * 4 + r;
                float v = acc[rr][cc][r] + bn;
                if (MODE == 0) {
                    int bb = m >> 9, l = m & 511, h = n >> 6, d = n & 63;
                    ((unsigned short*)out)[(((bb * NH + h) * SEQ) + l) * HD + d] = f2bf(v);
                } else {
                    ((float*)out)[m * DIM + n] = v;
                }
            }
        }
}

// ---------------- transpose V: [B,H,SEQ,HD] -> [B,H,HD,SEQ] ----------------
__global__ void k_vt(const unsigned short* __restrict__ v_ws, unsigned short* __restrict__ v_t) {
    int bh = blockIdx.x;
    int lk0 = blockIdx.y * 64;
    int t = threadIdx.x;
    const unsigned short* src = v_ws + bh * SEQ * HD;
    unsigned short* dst = v_t + bh * HD * SEQ;
#pragma unroll
    for (int i = 0; i < 2; ++i) {
        int e = i * 256 + t;            // 0..511
        int dh = e >> 3, c8 = e & 7;
        unsigned short tmp[8];
#pragma unroll
        for (int j = 0; j < 8; ++j)
            tmp[j] = src[(lk0 + c8 * 8 + j) * HD + dh];
        *(uint4*)(dst + dh * SEQ + lk0 + c8 * 8) = *(uint4*)tmp;
    }
}

// ---------------- attention: per (qtile32, h, b) ----------------
__global__ void __launch_bounds__(256) k_attn(const unsigned short* __restrict__ q_ws,
                                              const unsigned short* __restrict__ k_ws,
                                              const unsigned short* __restrict__ v_t,
                                              const float* __restrict__ bias_ws,
                                              unsigned short* __restrict__ attn_out) {
    __shared__ float sm[32 * 516 + 32];   // logits [32][516] + inv[32]
    int qt = blockIdx.x, h = blockIdx.y, b = blockIdx.z;
    int q0 = qt * 32;
    int t = threadIdx.x, lane = t & 63, w = t >> 6;
    int lrow = lane & 15, hi = lane >> 4;
    int bh = b * NH + h;
    const unsigned short* Q = q_ws + (bh * SEQ + q0) * HD;
    const unsigned short* K = k_ws + bh * SEQ * HD;
    const float* Bias = bias_ws + (h * SEQ + q0) * SEQ;

    // phase A: S = Q K^T * SCALE + bias  -> LDS (wave w owns cols [w*128, w*128+128))
    bf16x8 aq[2][2];
#pragma unroll
    for (int rt = 0; rt < 2; ++rt)
#pragma unroll
        for (int ds = 0; ds < 2; ++ds)
            aq[rt][ds] = *(const bf16x8*)(Q + (rt * 16 + lrow) * HD + ds * 32 + hi * 8);

#pragma unroll
    for (int ct = 0; ct < 8; ++ct) {
        f32x4 acc0 = {}, acc1 = {};
        int kk = w * 128 + ct * 16 + lrow;
#pragma unroll
        for (int ds = 0; ds < 2; ++ds) {
            bf16x8 bk = *(const bf16x8*)(K + kk * HD + ds * 32 + hi * 8);
            acc0 = MFMA16(aq[0][ds], bk, acc0, 0, 0, 0);
            acc1 = MFMA16(aq[1][ds], bk, acc1, 0, 0, 0);
        }
        int col = w * 128 + ct * 16 + lrow;
#pragma unroll
        for (int r = 0; r < 4; ++r) {
            int row0 = hi * 4 + r;
            sm[row0 * 516 + col] = acc0[r] * SCALE + Bias[row0 * SEQ + col];
            int row1 = 16 + hi * 4 + r;
            sm[row1 * 516 + col] = acc1[r] * SCALE + Bias[row1 * SEQ + col];
        }
    }
    __syncthreads();

    // phase B: row softmax (8 lanes per row, stride-8 column scan)
    {
        int row = t >> 3, seg = t & 7;
        float mx = -1e30f;
#pragma unroll 8
        for (int i = 0; i < 64; ++i)
            mx = fmaxf(mx, sm[row * 516 + seg + 8 * i]);
        mx = fmaxf(mx, __shfl_xor(mx, 1));
        mx = fmaxf(mx, __shfl_xor(mx, 2));
        mx = fmaxf(mx, __shfl_xor(mx, 4));
        float s = 0.f;
#pragma unroll 8
        for (int i = 0; i < 64; ++i) {
            int idx = row * 516 + seg + 8 * i;
            float pe = __expf(sm[idx] - mx);
            sm[idx] = pe;
            s += pe;
        }
        s += __shfl_xor(s, 1);
        s += __shfl_xor(s, 2);
        s += __shfl_xor(s, 4);
        if (seg == 0) sm[32 * 516 + row] = 1.0f / s;
    }
    __syncthreads();

    // phase C: O = P V  (wave w owns dh cols [w*16, w*16+16))
    const unsigned short* Vt = v_t + bh * HD * SEQ + (w * 16 + lrow) * SEQ;
    f32x4 oacc0 = {}, oacc1 = {};
    for (int kt = 0; kt < 16; ++kt) {
        bf16x8 bv = *(const bf16x8*)(Vt + kt * 32 + hi * 8);
#pragma unroll
        for (int rt = 0; rt < 2; ++rt) {
            const float* ps = &sm[(rt * 16 + lrow) * 516 + kt * 32 + hi * 8];
            float4 p0 = *(const float4*)(ps);
            float4 p1 = *(const float4*)(ps + 4);
            bf16x8 pa;
            pa[0] = (short)f2bf(p0.x); pa[1] = (short)f2bf(p0.y);
            pa[2] = (short)f2bf(p0.z); pa[3] = (short)f2bf(p0.w);
            pa[4] = (short)f2bf(p1.x); pa[5] = (short)f2bf(p1.y);
            pa[6] = (short)f2bf(p1.z); pa[7] = (short)f2bf(p1.w);
            if (rt == 0) oacc0 = MFMA16(pa, bv, oacc0, 0, 0, 0);
            else         oacc1 = MFMA16(pa, bv, oacc1, 0, 0, 0);
        }
    }
#pragma unroll
    for (int r = 0; r < 4; ++r) {
        int row0 = hi * 4 + r;
        float v0 = oacc0[r] * sm[32 * 516 + row0];
        attn_out[(b * SEQ + q0 + row0) * DIM + h * HD + w * 16 + lrow] = f2bf(v0);
        int row1 = 16 + hi * 4 + r;
        float v1 = oacc1[r] * sm[32 * 516 + row1];
        attn_out[(b * SEQ + q0 + row1) * DIM + h * HD + w * 16 + lrow] = f2bf(v1);
    }
}

extern "C" void kernel_launch(void* const* d_in, const int* in_sizes, int n_in,
                              void* d_out, int out_size, void* d_ws, size_t ws_size,
                              hipStream_t stream) {
    const float* query     = (const float*)d_in[0];
    const float* key_value = (const float*)d_in[1];
    const float* qc        = (const float*)d_in[2];
    const float* kc        = (const float*)d_in[3];
    const float* Wq        = (const float*)d_in[4];
    const float* bq        = (const float*)d_in[5];
    const float* Wk        = (const float*)d_in[6];
    const float* bk        = (const float*)d_in[7];
    const float* Wv        = (const float*)d_in[8];
    const float* bv        = (const float*)d_in[9];
    const float* Wo        = (const float*)d_in[10];
    const float* bo        = (const float*)d_in[11];
    const float* W1        = (const float*)d_in[12];
    const float* b1        = (const float*)d_in[13];
    const float* W2        = (const float*)d_in[14];
    const float* b2        = (const float*)d_in[15];

    char* ws = (char*)d_ws;
    unsigned short* Xq   = (unsigned short*)(ws + 0);          // 6291456 B (reused as attn_out)
    unsigned short* Xkv  = (unsigned short*)(ws + 6291456);    // 6291456 B (reused as v_t)
    unsigned short* WqT  = (unsigned short*)(ws + 12582912);
    unsigned short* WkT  = (unsigned short*)(ws + 13762560);
    unsigned short* WvT  = (unsigned short*)(ws + 14942208);
    unsigned short* WoT  = (unsigned short*)(ws + 16121856);
    unsigned short* q_ws = (unsigned short*)(ws + 17301504);
    unsigned short* k_ws = (unsigned short*)(ws + 23592960);
    unsigned short* v_ws = (unsigned short*)(ws + 29884416);
    float* bias_ws       = (float*)(ws + 36175872);            // 12582912 B
    float* P8            = (float*)(ws + 48758784);            // 24576 B
    unsigned short* W2f  = (unsigned short*)(ws + 48783360);   // 24576 B
    unsigned short* attn_out = Xq;   // Xq dead after Q projection
    unsigned short* v_t      = Xkv;  // Xkv dead after K/V projections

    k_convert<<<dim3(3072), dim3(256), 0, stream>>>(query, Xq, 786432);
    k_convert<<<dim3(3072), dim3(256), 0, stream>>>(key_value, Xkv, 786432);
    k_wt<<<dim3(24, 24), dim3(32, 8), 0, stream>>>(Wq, WqT);
    k_wt<<<dim3(24, 24), dim3(32, 8), 0, stream>>>(Wk, WkT);
    k_wt<<<dim3(24, 24), dim3(32, 8), 0, stream>>>(Wv, WvT);
    k_wt<<<dim3(24, 24), dim3(32, 8), 0, stream>>>(Wo, WoT);
    k_pack2<<<dim3(48), dim3(256), 0, stream>>>(W1, b1, W2, P8, W2f);
    k_mlp2<<<dim3(4096), dim3(256), 0, stream>>>(qc, kc, P8, W2f, b2, bias_ws);
    k_gemm<0><<<dim3(64, 12), dim3(256), 0, stream>>>(Xq, WqT, bq, q_ws);
    k_gemm<0><<<dim3(64, 12), dim3(256), 0, stream>>>(Xkv, WkT, bk, k_ws);
    k_gemm<0><<<dim3(64, 12), dim3(256), 0, stream>>>(Xkv, WvT, bv, v_ws);
    k_vt<<<dim3(96, 8), dim3(256), 0, stream>>>(v_ws, v_t);
    k_attn<<<dim3(16, NH, NB), dim3(256), 0, stream>>>(q_ws, k_ws, v_t, bias_ws, attn_out);
    k_gemm<1><<<dim3(64, 12), dim3(256), 0, stream>>>(attn_out, WoT, bo, d_out);
}

// Round 3
// 283.679 us; speedup vs baseline: 1.5761x; 1.2016x over previous
//
#include <hip/hip_runtime.h>
#include <hip/hip_bf16.h>
#include <stdint.h>

typedef __attribute__((ext_vector_type(4))) float f32x4;
typedef __attribute__((ext_vector_type(8))) short bf16x8;
typedef _Float16 f16;
typedef __attribute__((ext_vector_type(8))) _Float16 f16x8;
typedef decltype(__builtin_amdgcn_cvt_pkrtz(0.f, 0.f)) pk16;

#define DIM   768
#define NH    12
#define HD    64
#define NB    8
#define SEQ   512
#define SCALE 0.125f

#define MFMA16  __builtin_amdgcn_mfma_f32_16x16x32_bf16
#define MFMA16H __builtin_amdgcn_mfma_f32_16x16x32_f16

__device__ __forceinline__ unsigned short f2bf(float f) {
    union { float f; uint32_t u; } v; v.f = f;
    uint32_t u = v.u;
    return (unsigned short)((u + 0x7FFFu + ((u >> 16) & 1u)) >> 16);
}

// gelu tanh-approx: x * sigmoid(2*0.7978845608*(x + 0.044715 x^3))
//   = x * rcp(1 + exp2(x*(-2.3022077 - 0.1029433 x^2)))
__device__ __forceinline__ float gelu_f(float x) {
    float pp = x * x;
    float poly = __builtin_fmaf(pp, -0.1029433f, -2.3022077f);
    float ev = __builtin_amdgcn_exp2f(x * poly);
    return x * __builtin_amdgcn_rcpf(1.0f + ev);
}

// ---------------- prep: f32 -> bf16 convert ----------------
__global__ void k_convert(const float* __restrict__ in, unsigned short* __restrict__ out, int n4) {
    int i = blockIdx.x * blockDim.x + threadIdx.x;
    if (i >= n4) return;
    float4 f = reinterpret_cast<const float4*>(in)[i];
    ushort4 o;
    o.x = f2bf(f.x); o.y = f2bf(f.y); o.z = f2bf(f.z); o.w = f2bf(f.w);
    reinterpret_cast<ushort4*>(out)[i] = o;
}

// ---------------- prep: W[768][768] f32 -> WT[768][768] bf16 (transposed) ----------------
__global__ void k_wt(const float* __restrict__ W, unsigned short* __restrict__ WT) {
    __shared__ float t[32][33];
    int n0 = blockIdx.x * 32, k0 = blockIdx.y * 32;
    int tx = threadIdx.x, ty = threadIdx.y; // 32 x 8
#pragma unroll
    for (int j = 0; j < 4; ++j)
        t[ty + 8 * j][tx] = W[(k0 + ty + 8 * j) * DIM + n0 + tx];
    __syncthreads();
#pragma unroll
    for (int j = 0; j < 4; ++j)
        WT[(n0 + ty + 8 * j) * DIM + k0 + tx] = f2bf(t[tx][ty + 8 * j]);
}

// ---------------- prep: pack MLP param tables (f16 MFMA fragments) ----------------
// W1tab[48][64][8]: tile t, lane(hi,m): e -> f=hi*8+e (only hi==0 nonzero):
//   f<6: W1[f][u=16t+m], f==6: b1[u], f==7: 0
// W2tab[24][64][8]: chunk j, lane(g,h): e -> u = 32j + (e>>2)*16 + 4g + (e&3):
//   h<12 ? W2[u][h] : 0
__global__ void k_pack3(const float* __restrict__ W1, const float* __restrict__ b1,
                        const float* __restrict__ W2, f16* __restrict__ W1tab,
                        f16* __restrict__ W2tab) {
    int i = blockIdx.x * 256 + threadIdx.x;
    if (i < 3072) {
        int lane = i & 63;
        int hi = lane >> 4, m = lane & 15;
        int u = (i >> 6) * 16 + m;
#pragma unroll
        for (int e = 0; e < 8; ++e) {
            float v = 0.f;
            if (hi == 0) {
                if (e < 6) v = W1[e * DIM + u];
                else if (e == 6) v = b1[u];
            }
            W1tab[i * 8 + e] = (f16)v;
        }
    } else if (i < 4608) {
        int i2 = i - 3072;
        int j = i2 >> 6, lane = i2 & 63;
        int g = lane >> 4, h = lane & 15;
#pragma unroll
        for (int e = 0; e < 8; ++e) {
            int u = 32 * j + ((e >> 2) << 4) + (g << 2) + (e & 3);
            float v = (h < 12) ? W2[u * 12 + h] : 0.f;
            W2tab[i2 * 8 + e] = (f16)v;
        }
    }
}

// ---------------- pairwise bias MLP, fully MFMA-ized ----------------
__global__ void __launch_bounds__(256) k_mlp3(const float* __restrict__ qc, const float* __restrict__ kc,
                                              const f16x8* __restrict__ W1tab,   // [48][64]
                                              const f16x8* __restrict__ W2tab,   // [24][64]
                                              const float* __restrict__ b2,
                                              float* __restrict__ bias_out) {
    int t = threadIdx.x, lane = t & 63, w = t >> 6;
    int hi = lane >> 4, m = lane & 15;
    int p0 = blockIdx.x * 64 + w * 16;
    int pair = p0 + m;
    int qi = pair >> 9, ki = pair & 511;
    float dx = qc[2 * qi] - kc[2 * ki];
    float dy = qc[2 * qi + 1] - kc[2 * ki + 1];

    // rel fragment (B operand, n=pair): features live in hi==0's k-slots
    union { f16x8 v; pk16 h2[4]; } rf;
    {
        f16x8 z = {};
        rf.v = z;
    }
    if (hi == 0) {
        rf.h2[0] = __builtin_amdgcn_cvt_pkrtz(dx, dy);
        rf.h2[1] = __builtin_amdgcn_cvt_pkrtz(fabsf(dx), fabsf(dy));
        rf.h2[2] = __builtin_amdgcn_cvt_pkrtz(dx * dx, dy * dy);
        rf.h2[3] = __builtin_amdgcn_cvt_pkrtz(1.0f, 0.0f);
    }

    float b2h = (m < 12) ? b2[m] : 0.f;
    f32x4 acc = {b2h, b2h, b2h, b2h};
    const f32x4 zero = {};
    const f16x8* w1p = W1tab + lane;
    const f16x8* w2p = W2tab + lane;

#pragma unroll 2
    for (int j = 0; j < 24; ++j) {
        f16x8 a0  = w1p[(2 * j) * 64];
        f16x8 a1  = w1p[(2 * j + 1) * 64];
        f16x8 w2v = w2p[j * 64];
        // pre for u-tiles 2j, 2j+1: D col=pair(lane&15), row=u_local=hi*4+r
        f32x4 pre0 = MFMA16H(a0, rf.v, zero, 0, 0, 0);
        f32x4 pre1 = MFMA16H(a1, rf.v, zero, 0, 0, 0);
        float g0 = gelu_f(pre0[0]), g1 = gelu_f(pre0[1]);
        float g2 = gelu_f(pre0[2]), g3 = gelu_f(pre0[3]);
        float g4 = gelu_f(pre1[0]), g5 = gelu_f(pre1[1]);
        float g6 = gelu_f(pre1[2]), g7 = gelu_f(pre1[3]);
        union { f16x8 v; pk16 h2[4]; } pa;
        pa.h2[0] = __builtin_amdgcn_cvt_pkrtz(g0, g1);
        pa.h2[1] = __builtin_amdgcn_cvt_pkrtz(g2, g3);
        pa.h2[2] = __builtin_amdgcn_cvt_pkrtz(g4, g5);
        pa.h2[3] = __builtin_amdgcn_cvt_pkrtz(g6, g7);
        // bias accumulate: A=pa (m=pair), B=W2 frag (n=h), k-slots = u (same map as W2tab)
        acc = MFMA16H(pa.v, w2v, acc, 0, 0, 0);
    }
    // D: col=lane&15=h, row=hi*4+r = pair-local
    if (m < 12) {
        float4 o4 = {acc[0], acc[1], acc[2], acc[3]};
        *reinterpret_cast<float4*>(bias_out + m * (SEQ * SEQ) + p0 + hi * 4) = o4;
    }
}

// ---------------- GEMM: C[m][n] = sum_k X[m][k]*WT[n][k] + bias[n] ----------------
// MODE 0: store bf16 to [B][NH][SEQ][HD] (m->(b,l), n->(h,d));  MODE 1: store f32 row-major [m][n]
template <int MODE>
__global__ void __launch_bounds__(256) k_gemm(const unsigned short* __restrict__ X,
                                              const unsigned short* __restrict__ WT,
                                              const float* __restrict__ bias, void* __restrict__ out) {
    int m0 = blockIdx.x * 64, n0 = blockIdx.y * 64;
    int t = threadIdx.x, lane = t & 63, w = t >> 6;
    int rt2 = w >> 1, ct2 = w & 1;
    int lrow = lane & 15, hi = lane >> 4;
    f32x4 acc[2][2] = {};
    const unsigned short* Xp = X + (m0 + rt2 * 32 + lrow) * DIM + hi * 8;
    const unsigned short* Wp = WT + (n0 + ct2 * 32 + lrow) * DIM + hi * 8;
#pragma unroll 4
    for (int k0 = 0; k0 < DIM; k0 += 32) {
        bf16x8 a0 = *(const bf16x8*)(Xp + k0);
        bf16x8 a1 = *(const bf16x8*)(Xp + 16 * DIM + k0);
        bf16x8 b0 = *(const bf16x8*)(Wp + k0);
        bf16x8 b1 = *(const bf16x8*)(Wp + 16 * DIM + k0);
        acc[0][0] = MFMA16(a0, b0, acc[0][0], 0, 0, 0);
        acc[0][1] = MFMA16(a0, b1, acc[0][1], 0, 0, 0);
        acc[1][0] = MFMA16(a1, b0, acc[1][0], 0, 0, 0);
        acc[1][1] = MFMA16(a1, b1, acc[1][1], 0, 0, 0);
    }
#pragma unroll
    for (int rr = 0; rr < 2; ++rr)
#pragma unroll
        for (int cc = 0; cc < 2; ++cc) {
            int n = n0 + ct2 * 32 + cc * 16 + lrow;
            float bn = bias[n];
#pragma unroll
            for (int r = 0; r < 4; ++r) {
                int m = m0 + rt2 * 32 + rr * 16 + hi * 4 + r;
                float v = acc[rr][cc][r] + bn;
                if (MODE == 0) {
                    int bb = m >> 9, l = m & 511, h = n >> 6, d = n & 63;
                    ((unsigned short*)out)[(((bb * NH + h) * SEQ) + l) * HD + d] = f2bf(v);
                } else {
                    ((float*)out)[m * DIM + n] = v;
                }
            }
        }
}

// ---------------- transpose V: [B,H,SEQ,HD] -> [B,H,HD,SEQ] ----------------
__global__ void k_vt(const unsigned short* __restrict__ v_ws, unsigned short* __restrict__ v_t) {
    int bh = blockIdx.x;
    int lk0 = blockIdx.y * 64;
    int t = threadIdx.x;
    const unsigned short* src = v_ws + bh * SEQ * HD;
    unsigned short* dst = v_t + bh * HD * SEQ;
#pragma unroll
    for (int i = 0; i < 2; ++i) {
        int e = i * 256 + t;            // 0..511
        int dh = e >> 3, c8 = e & 7;
        unsigned short tmp[8];
#pragma unroll
        for (int j = 0; j < 8; ++j)
            tmp[j] = src[(lk0 + c8 * 8 + j) * HD + dh];
        *(uint4*)(dst + dh * SEQ + lk0 + c8 * 8) = *(uint4*)tmp;
    }
}

// ---------------- attention: per (qtile32, h, b) ----------------
__global__ void __launch_bounds__(256) k_attn(const unsigned short* __restrict__ q_ws,
                                              const unsigned short* __restrict__ k_ws,
                                              const unsigned short* __restrict__ v_t,
                                              const float* __restrict__ bias_ws,
                                              unsigned short* __restrict__ attn_out) {
    __shared__ float sm[32 * 516 + 32];   // logits [32][516] + inv[32]
    int qt = blockIdx.x, h = blockIdx.y, b = blockIdx.z;
    int q0 = qt * 32;
    int t = threadIdx.x, lane = t & 63, w = t >> 6;
    int lrow = lane & 15, hi = lane >> 4;
    int bh = b * NH + h;
    const unsigned short* Q = q_ws + (bh * SEQ + q0) * HD;
    const unsigned short* K = k_ws + bh * SEQ * HD;
    const float* Bias = bias_ws + (h * SEQ + q0) * SEQ;

    // phase A: S = Q K^T * SCALE + bias  -> LDS (wave w owns cols [w*128, w*128+128))
    bf16x8 aq[2][2];
#pragma unroll
    for (int rt = 0; rt < 2; ++rt)
#pragma unroll
        for (int ds = 0; ds < 2; ++ds)
            aq[rt][ds] = *(const bf16x8*)(Q + (rt * 16 + lrow) * HD + ds * 32 + hi * 8);

#pragma unroll
    for (int ct = 0; ct < 8; ++ct) {
        f32x4 acc0 = {}, acc1 = {};
        int kk = w * 128 + ct * 16 + lrow;
#pragma unroll
        for (int ds = 0; ds < 2; ++ds) {
            bf16x8 bk = *(const bf16x8*)(K + kk * HD + ds * 32 + hi * 8);
            acc0 = MFMA16(aq[0][ds], bk, acc0, 0, 0, 0);
            acc1 = MFMA16(aq[1][ds], bk, acc1, 0, 0, 0);
        }
        int col = w * 128 + ct * 16 + lrow;
#pragma unroll
        for (int r = 0; r < 4; ++r) {
            int row0 = hi * 4 + r;
            sm[row0 * 516 + col] = acc0[r] * SCALE + Bias[row0 * SEQ + col];
            int row1 = 16 + hi * 4 + r;
            sm[row1 * 516 + col] = acc1[r] * SCALE + Bias[row1 * SEQ + col];
        }
    }
    __syncthreads();

    // phase B: row softmax (8 lanes per row, stride-8 column scan)
    {
        int row = t >> 3, seg = t & 7;
        float mx = -1e30f;
#pragma unroll 8
        for (int i = 0; i < 64; ++i)
            mx = fmaxf(mx, sm[row * 516 + seg + 8 * i]);
        mx = fmaxf(mx, __shfl_xor(mx, 1));
        mx = fmaxf(mx, __shfl_xor(mx, 2));
        mx = fmaxf(mx, __shfl_xor(mx, 4));
        float s = 0.f;
#pragma unroll 8
        for (int i = 0; i < 64; ++i) {
            int idx = row * 516 + seg + 8 * i;
            float pe = __expf(sm[idx] - mx);
            sm[idx] = pe;
            s += pe;
        }
        s += __shfl_xor(s, 1);
        s += __shfl_xor(s, 2);
        s += __shfl_xor(s, 4);
        if (seg == 0) sm[32 * 516 + row] = 1.0f / s;
    }
    __syncthreads();

    // phase C: O = P V  (wave w owns dh cols [w*16, w*16+16))
    const unsigned short* Vt = v_t + bh * HD * SEQ + (w * 16 + lrow) * SEQ;
    f32x4 oacc0 = {}, oacc1 = {};
    for (int kt = 0; kt < 16; ++kt) {
        bf16x8 bv = *(const bf16x8*)(Vt + kt * 32 + hi * 8);
#pragma unroll
        for (int rt = 0; rt < 2; ++rt) {
            const float* ps = &sm[(rt * 16 + lrow) * 516 + kt * 32 + hi * 8];
            float4 p0 = *(const float4*)(ps);
            float4 p1 = *(const float4*)(ps + 4);
            bf16x8 pa;
            pa[0] = (short)f2bf(p0.x); pa[1] = (short)f2bf(p0.y);
            pa[2] = (short)f2bf(p0.z); pa[3] = (short)f2bf(p0.w);
            pa[4] = (short)f2bf(p1.x); pa[5] = (short)f2bf(p1.y);
            pa[6] = (short)f2bf(p1.z); pa[7] = (short)f2bf(p1.w);
            if (rt == 0) oacc0 = MFMA16(pa, bv, oacc0, 0, 0, 0);
            else         oacc1 = MFMA16(pa, bv, oacc1, 0, 0, 0);
        }
    }
#pragma unroll
    for (int r = 0; r < 4; ++r) {
        int row0 = hi * 4 + r;
        float v0 = oacc0[r] * sm[32 * 516 + row0];
        attn_out[(b * SEQ + q0 + row0) * DIM + h * HD + w * 16 + lrow] = f2bf(v0);
        int row1 = 16 + hi * 4 + r;
        float v1 = oacc1[r] * sm[32 * 516 + row1];
        attn_out[(b * SEQ + q0 + row1) * DIM + h * HD + w * 16 + lrow] = f2bf(v1);
    }
}

extern "C" void kernel_launch(void* const* d_in, const int* in_sizes, int n_in,
                              void* d_out, int out_size, void* d_ws, size_t ws_size,
                              hipStream_t stream) {
    const float* query     = (const float*)d_in[0];
    const float* key_value = (const float*)d_in[1];
    const float* qc        = (const float*)d_in[2];
    const float* kc        = (const float*)d_in[3];
    const float* Wq        = (const float*)d_in[4];
    const float* bq        = (const float*)d_in[5];
    const float* Wk        = (const float*)d_in[6];
    const float* bk        = (const float*)d_in[7];
    const float* Wv        = (const float*)d_in[8];
    const float* bv        = (const float*)d_in[9];
    const float* Wo        = (const float*)d_in[10];
    const float* bo        = (const float*)d_in[11];
    const float* W1        = (const float*)d_in[12];
    const float* b1        = (const float*)d_in[13];
    const float* W2        = (const float*)d_in[14];
    const float* b2        = (const float*)d_in[15];

    char* ws = (char*)d_ws;
    unsigned short* Xq   = (unsigned short*)(ws + 0);          // reused as attn_out
    unsigned short* Xkv  = (unsigned short*)(ws + 6291456);    // reused as v_t
    unsigned short* WqT  = (unsigned short*)(ws + 12582912);
    unsigned short* WkT  = (unsigned short*)(ws + 13762560);
    unsigned short* WvT  = (unsigned short*)(ws + 14942208);
    unsigned short* WoT  = (unsigned short*)(ws + 16121856);
    unsigned short* q_ws = (unsigned short*)(ws + 17301504);
    unsigned short* k_ws = (unsigned short*)(ws + 23592960);
    unsigned short* v_ws = (unsigned short*)(ws + 29884416);
    float* bias_ws       = (float*)(ws + 36175872);            // 12582912 B
    // MLP f16 tables live in the (currently dead) q_ws region; dead after k_mlp3.
    f16* W1tab           = (f16*)(ws + 17301504);              // 49152 B
    f16* W2tab           = (f16*)(ws + 17350656);              // 24576 B
    unsigned short* attn_out = Xq;   // Xq dead after Q projection
    unsigned short* v_t      = Xkv;  // Xkv dead after K/V projections

    k_convert<<<dim3(3072), dim3(256), 0, stream>>>(query, Xq, 786432);
    k_convert<<<dim3(3072), dim3(256), 0, stream>>>(key_value, Xkv, 786432);
    k_wt<<<dim3(24, 24), dim3(32, 8), 0, stream>>>(Wq, WqT);
    k_wt<<<dim3(24, 24), dim3(32, 8), 0, stream>>>(Wk, WkT);
    k_wt<<<dim3(24, 24), dim3(32, 8), 0, stream>>>(Wv, WvT);
    k_wt<<<dim3(24, 24), dim3(32, 8), 0, stream>>>(Wo, WoT);
    k_pack3<<<dim3(18), dim3(256), 0, stream>>>(W1, b1, W2, W1tab, W2tab);
    k_mlp3<<<dim3(4096), dim3(256), 0, stream>>>(qc, kc, (const f16x8*)W1tab, (const f16x8*)W2tab, b2, bias_ws);
    k_gemm<0><<<dim3(64, 12), dim3(256), 0, stream>>>(Xq, WqT, bq, q_ws);
    k_gemm<0><<<dim3(64, 12), dim3(256), 0, stream>>>(Xkv, WkT, bk, k_ws);
    k_gemm<0><<<dim3(64, 12), dim3(256), 0, stream>>>(Xkv, WvT, bv, v_ws);
    k_vt<<<dim3(96, 8), dim3(256), 0, stream>>>(v_ws, v_t);
    k_attn<<<dim3(16, NH, NB), dim3(256), 0, stream>>>(q_ws, k_ws, v_t, bias_ws, attn_out);
    k_gemm<1><<<dim3(64, 12), dim3(256), 0, stream>>>(attn_out, WoT, bo, d_out);
}